// Round 5
// baseline (42298.709 us; speedup 1.0000x reference)
//
#include <hip/hip_runtime.h>
#include <math.h>

typedef unsigned int u32;
typedef unsigned long long ull;
typedef float f4v __attribute__((ext_vector_type(4)));

#define T_     1024
#define N_     128
#define V_     35
#define H_     512
#define VS_    128
#define KS_    128
#define MAXLEN 250
#define NBLK   256
#define ASTR   1152   // A row: [emb(512) | vm(128) | h1(512)]

// ---- workspace layout (bytes) ----
#define OFF_FLAG  512
#define OFF_SLOTS 1024               // 256 slots, 64B apart (16 KB)
#define OFF_A0    20480
#define SZ_A      (N_*ASTR*4)        // 589824
#define OFF_A1    (OFF_A0+SZ_A)     // total ~1.2 MB

__device__ __forceinline__ float sigf(float x){ return 1.0f/(1.0f+expf(-x)); }
__device__ __forceinline__ float dot4(float4 a, float4 b){ return a.x*b.x + a.y*b.y + a.z*b.z + a.w*b.w; }
__device__ __forceinline__ float dot4v(f4v a, float4 b){ return a.x*b.x + a.y*b.y + a.z*b.z + a.w*b.w; }

// Coherent (sc1) accessors: bypass stale L1/L2, hit the always-coherent L3.
// Used ONLY for cross-block mutable state; read-only data keeps plain cached
// loads so weights persist in L2 across steps (no fences/invalidates anywhere).
__device__ __forceinline__ float cohloadf(const float* p){
  return __hip_atomic_load(p, __ATOMIC_RELAXED, __HIP_MEMORY_SCOPE_AGENT);
}
__device__ __forceinline__ void cohstoref(float* p, float v){
  __hip_atomic_store(p, v, __ATOMIC_RELAXED, __HIP_MEMORY_SCOPE_AGENT);
}
__device__ __forceinline__ float4 cohload4(const float* p){
  const ull* q = (const ull*)p;
  ull a = __hip_atomic_load(q,   __ATOMIC_RELAXED, __HIP_MEMORY_SCOPE_AGENT);
  ull b = __hip_atomic_load(q+1, __ATOMIC_RELAXED, __HIP_MEMORY_SCOPE_AGENT);
  float2 x = __builtin_bit_cast(float2, a), y = __builtin_bit_cast(float2, b);
  return make_float4(x.x, x.y, y.x, y.y);
}

// Two-level flag barrier, NO cache-invalidating fences. Publish ordering comes
// from __syncthreads' implicit s_waitcnt vmcnt(0) before s_barrier: all sc1
// state stores have reached the coherence point before thread 0 signals.
__device__ __forceinline__ void gbar(u32* slots, u32* bflag, u32 ep, int b){
  __syncthreads();
  if (threadIdx.x == 0)
    __hip_atomic_store(&slots[(size_t)b*16], ep, __ATOMIC_RELAXED, __HIP_MEMORY_SCOPE_AGENT);
  if (b == 0){
    u32* ms = &slots[(size_t)threadIdx.x*16];
    while (__hip_atomic_load(ms, __ATOMIC_RELAXED, __HIP_MEMORY_SCOPE_AGENT) < ep)
      __builtin_amdgcn_s_sleep(1);
    __syncthreads();
    if (threadIdx.x == 0)
      __hip_atomic_store(bflag, ep, __ATOMIC_RELAXED, __HIP_MEMORY_SCOPE_AGENT);
  } else if (threadIdx.x == 0){
    while (__hip_atomic_load(bflag, __ATOMIC_RELAXED, __HIP_MEMORY_SCOPE_AGENT) < ep)
      __builtin_amdgcn_s_sleep(1);
  }
  __syncthreads();
}

// ---- one-time prep: values_mean + A0 init. Kernel-boundary release flushes
// these plain writes to L3, where the decoder's sc1 loads will see them. ----
__global__ void prep_state(const float* __restrict__ val, const float* __restrict__ emb,
                           char* __restrict__ ws){
  __shared__ float part[256];
  float* A0 = (float*)(ws + OFF_A0);
  float* A1 = (float*)(ws + OFF_A1);
  const int n = blockIdx.x, tid = threadIdx.x;
  const int c = tid >> 7, v = tid & 127;
  float acc = 0.f;
  const float* vp = val + (size_t)(c*512)*N_*VS_ + (size_t)n*VS_ + v;
  #pragma unroll 8
  for (int t = 0; t < 512; ++t) acc += vp[(size_t)t*N_*VS_];
  part[tid] = acc;
  __syncthreads();
  if (tid < 128){
    float vm = (part[tid] + part[tid+128]) * (1.0f/1024.0f);
    A0[(size_t)n*ASTR + 512 + tid] = vm;
    A1[(size_t)n*ASTR + 512 + tid] = vm;
  }
  A0[(size_t)n*ASTR + tid]       = emb[tid];        // emb[tok0=0]
  A0[(size_t)n*ASTR + 256 + tid] = emb[256 + tid];
  A0[(size_t)n*ASTR + 640 + tid] = 0.f;             // h1 = 0
  A0[(size_t)n*ASTR + 896 + tid] = 0.f;
}

// ---- persistent decoder: 256 blocks x 256 threads, 2 grid barriers/step ----
__global__ __launch_bounds__(256, 1) void decoder_main(
  const float* __restrict__ key, const float* __restrict__ val,
  const int* __restrict__ lens, const float* __restrict__ emb,
  const float* __restrict__ W_ih1, const float* __restrict__ W_hh1,
  const float* __restrict__ b_ih1, const float* __restrict__ b_hh1,
  const float* __restrict__ W_ih2, const float* __restrict__ W_hh2,
  const float* __restrict__ b_ih2, const float* __restrict__ b_hh2,
  const float* __restrict__ W_out, const float* __restrict__ b_out,
  float* __restrict__ out, char* __restrict__ ws)
{
  __shared__ __align__(16) float smem[5504];  // A: As[16][68]+Ws[64][68]; BC reuses
  __shared__ float c1_keep[256];              // block-private LSTM1 cell state
  __shared__ float h2_keep[128];              // block-private h2 (blocks 0..127)
  __shared__ float c2_keep[128];
  float* As = smem;               // 16*68 = 1088
  float* Ws = smem + 1088;        // 64*68 = 4352

  u32* bflag = (u32*)(ws + OFF_FLAG);
  u32* slots = (u32*)(ws + OFF_SLOTS);
  float* A0 = (float*)(ws + OFF_A0);
  float* A1 = (float*)(ws + OFF_A1);

  const int b = blockIdx.x;
  const int tid = threadIdx.x;

  c1_keep[tid] = 0.f;
  if (tid < 128){ h2_keep[tid] = 0.f; c2_keep[tid] = 0.f; }

  float* Acur = A0; float* Anxt = A1;
  u32 ep = 0;

  #pragma unroll 1
  for (int step = 0; step < MAXLEN; ++step){
    // ============ Phase A: LSTM1 gates, all 256 blocks ============
    // G[128 x 2048] (cols reordered c=4*hid+gate), K=1152. Tile 16x64.
    // 4x4 register blocking; wave = k-quarter; LDS reduce at end.
    {
      const int rt = b >> 5, ct = b & 31;
      const int row0 = rt*16, c0 = ct*64;
      const int lane = tid & 63, qw = tid >> 6;   // wave id = k-quarter
      const int r_g = lane >> 4;                  // rows r_g + 4i
      const int c_g = lane & 15;                  // cols c_g + 16j
      const int c_st = tid >> 2, seg = tid & 3;   // weight staging
      const int sgl = c0 + c_st, shh = sgl >> 2, sgg = sgl & 3;
      const float* wsx = W_ih1 + (size_t)(sgg*H_ + shh)*640 + seg*16;
      const float* wsh = W_hh1 + (size_t)(sgg*H_ + shh)*512 + seg*16;
      const int r_st = tid >> 4, kq_st = tid & 15; // activation staging
      const float* arow = Acur + (size_t)(row0 + r_st)*ASTR + kq_st*4;

      float acc[4][4];
      #pragma unroll
      for (int i = 0; i < 4; ++i){ acc[i][0]=0.f; acc[i][1]=0.f; acc[i][2]=0.f; acc[i][3]=0.f; }

      float4 w0,w1,w2,w3, aR;
      w0 = ((const float4*)wsx)[0]; w1 = ((const float4*)wsx)[1];
      w2 = ((const float4*)wsx)[2]; w3 = ((const float4*)wsx)[3];
      aR = cohload4(arow);

      #pragma unroll 1
      for (int ch = 0; ch < 18; ++ch){
        __syncthreads();
        { float* wd = Ws + c_st*68 + seg*16;
          ((float4*)wd)[0]=w0; ((float4*)wd)[1]=w1; ((float4*)wd)[2]=w2; ((float4*)wd)[3]=w3;
          *(float4*)(As + r_st*68 + kq_st*4) = aR;
        }
        __syncthreads();
        if (ch < 17){
          int kb = (ch+1)*64;
          const float* p = (kb < 640) ? (wsx + kb) : (wsh + (kb-640));
          w0 = ((const float4*)p)[0]; w1 = ((const float4*)p)[1];
          w2 = ((const float4*)p)[2]; w3 = ((const float4*)p)[3];
          aR = cohload4(arow + kb);
        }
        #pragma unroll
        for (int kq = 0; kq < 4; ++kq){
          const int t4 = (qw*4 + kq)*4;
          float4 wv0 = *(const float4*)(Ws + (c_g   )*68 + t4);
          float4 wv1 = *(const float4*)(Ws + (c_g+16)*68 + t4);
          float4 wv2 = *(const float4*)(Ws + (c_g+32)*68 + t4);
          float4 wv3 = *(const float4*)(Ws + (c_g+48)*68 + t4);
          float4 av0 = *(const float4*)(As + (r_g   )*68 + t4);
          float4 av1 = *(const float4*)(As + (r_g+ 4)*68 + t4);
          float4 av2 = *(const float4*)(As + (r_g+ 8)*68 + t4);
          float4 av3 = *(const float4*)(As + (r_g+12)*68 + t4);
          acc[0][0]+=dot4(av0,wv0); acc[0][1]+=dot4(av0,wv1); acc[0][2]+=dot4(av0,wv2); acc[0][3]+=dot4(av0,wv3);
          acc[1][0]+=dot4(av1,wv0); acc[1][1]+=dot4(av1,wv1); acc[1][2]+=dot4(av1,wv2); acc[1][3]+=dot4(av1,wv3);
          acc[2][0]+=dot4(av2,wv0); acc[2][1]+=dot4(av2,wv1); acc[2][2]+=dot4(av2,wv2); acc[2][3]+=dot4(av2,wv3);
          acc[3][0]+=dot4(av3,wv0); acc[3][1]+=dot4(av3,wv1); acc[3][2]+=dot4(av3,wv2); acc[3][3]+=dot4(av3,wv3);
        }
      }
      __syncthreads();
      float* Red = Ws;   // [a(16)][q(4)][lane(64)] = 4096 floats, reuse Ws
      #pragma unroll
      for (int ri = 0; ri < 4; ++ri)
        #pragma unroll
        for (int ci = 0; ci < 4; ++ci)
          Red[((ri*4+ci)*4 + qw)*64 + lane] = acc[ri][ci];
      __syncthreads();
      { // reduce 4 partials + bias -> Gs (= As region)
        const int l2 = tid & 63, g = tid >> 6;
        const int row_l = (l2 >> 4) + 4*g;
        #pragma unroll
        for (int j = 0; j < 4; ++j){
          const int a = g*4 + j;
          const float* rp = Red + a*256 + l2;
          float s = rp[0] + rp[64] + rp[128] + rp[192];
          const int col_l = (l2 & 15) + 16*j;
          const int cgl = c0 + col_l, chh2 = cgl >> 2, cgg2 = cgl & 3;
          s += b_ih1[cgg2*H_ + chh2] + b_hh1[cgg2*H_ + chh2];
          As[row_l*68 + col_l] = s;
        }
      }
      __syncthreads();
      { const int r = tid >> 4, hl = tid & 15;
        float4 q = *(const float4*)(As + r*68 + hl*4);   // i,f,g,o
        const int row = row0 + r, hid = ct*16 + hl;
        float cold = c1_keep[tid];
        float cn = sigf(q.y)*cold + sigf(q.x)*tanhf(q.z);
        float hn = sigf(q.w)*tanhf(cn);
        c1_keep[tid] = cn;
        cohstoref(Anxt + (size_t)row*ASTR + 640 + hid, hn);  // h1_s -> next A
      }
    }
    gbar(slots, bflag, ++ep, b);

    // ===== Phase BC (blocks 0..127): LSTM2 + attention + argmax + emb =====
    if (b < 128){
      const int n = b;
      float* xs  = smem;         // [640] = [h1 | h2old]
      float* G2  = smem + 640;   // [512] gate pre-acts
      float* h2s = smem + 1152;  // [128]
      float* Es  = smem + 1280;  // [1024]
      float* red = smem + 2304;  // [256]
      float* Cs  = smem + 2560;  // [8][128]
      float* Zs  = smem + 3584;  // [256] = [h2 | ctx]
      float* Pr  = smem + 3840;  // [64] logits
      const int len = lens[n];
      xs[tid]       = cohloadf(Anxt + (size_t)n*ASTR + 640 + tid);
      xs[256 + tid] = cohloadf(Anxt + (size_t)n*ASTR + 896 + tid);
      if (tid < 128) xs[512 + tid] = h2_keep[tid];
      __syncthreads();
      { // LSTM2 gates: 2 cols/thread, W2 streamed from L2-resident cache
        float fa = b_ih2[tid]     + b_hh2[tid];
        float fb = b_ih2[256+tid] + b_hh2[256+tid];
        const float4* wa = (const float4*)(W_ih2 + (size_t)tid*512);
        const float4* wb = (const float4*)(W_ih2 + (size_t)(256+tid)*512);
        const float4* xv4 = (const float4*)xs;
        #pragma unroll 8
        for (int k4 = 0; k4 < 128; ++k4){
          float4 xv = xv4[k4];
          fa += dot4(wa[k4], xv);
          fb += dot4(wb[k4], xv);
        }
        const float4* ha = (const float4*)(W_hh2 + (size_t)tid*128);
        const float4* hb = (const float4*)(W_hh2 + (size_t)(256+tid)*128);
        #pragma unroll 8
        for (int k4 = 0; k4 < 32; ++k4){
          float4 xv = xv4[128 + k4];
          fa += dot4(ha[k4], xv);
          fb += dot4(hb[k4], xv);
        }
        G2[tid] = fa; G2[256+tid] = fb;
      }
      __syncthreads();
      if (tid < 128){
        float gi = G2[tid], gf = G2[128+tid], gg = G2[256+tid], go = G2[384+tid];
        float cold = c2_keep[tid];
        float cn = sigf(gf)*cold + sigf(gi)*tanhf(gg);
        float hn = sigf(go)*tanhf(cn);
        c2_keep[tid] = cn; h2_keep[tid] = hn;
        h2s[tid] = hn; Zs[tid] = hn;
      }
      __syncthreads();
      // attention energies (nontemporal: don't evict weights from L2)
      for (int t0 = 0; t0 < 4; ++t0){
        int t = t0*256 + tid;
        if (t < len){
          const f4v* kp = (const f4v*)(key + ((size_t)t*N_ + n)*KS_);
          float e = 0.f;
          #pragma unroll
          for (int k4 = 0; k4 < 32; ++k4){
            f4v q = __builtin_nontemporal_load(kp + k4);
            e += q.x*h2s[k4*4+0] + q.y*h2s[k4*4+1] + q.z*h2s[k4*4+2] + q.w*h2s[k4*4+3];
          }
          Es[t] = e;
        }
      }
      __syncthreads();
      float lm = -3.0e38f;
      for (int t = tid; t < len; t += 256) lm = fmaxf(lm, Es[t]);
      red[tid] = lm; __syncthreads();
      for (int s2 = 128; s2 > 0; s2 >>= 1){ if (tid < s2) red[tid] = fmaxf(red[tid], red[tid+s2]); __syncthreads(); }
      const float m = red[0];
      __syncthreads();
      float ls = 0.f;
      for (int t = tid; t < len; t += 256){ float p = expf(Es[t]-m); Es[t] = p; ls += p; }
      red[tid] = ls; __syncthreads();
      for (int s2 = 128; s2 > 0; s2 >>= 1){ if (tid < s2) red[tid] += red[tid+s2]; __syncthreads(); }
      const float inv = 1.0f / red[0];
      __syncthreads();
      { // ctx: 8-way t-split, float4 in v
        const int part = tid >> 5, v4 = (tid & 31)*4;
        float cA=0.f,cB=0.f,cC=0.f,cD=0.f;
        for (int t = part; t < len; t += 8){
          float p = Es[t];
          f4v u = __builtin_nontemporal_load((const f4v*)(val + ((size_t)t*N_ + n)*VS_ + v4));
          cA += p*u.x; cB += p*u.y; cC += p*u.z; cD += p*u.w;
        }
        Cs[part*128 + v4+0]=cA; Cs[part*128 + v4+1]=cB; Cs[part*128 + v4+2]=cC; Cs[part*128 + v4+3]=cD;
      }
      __syncthreads();
      if (tid < 128){
        float s = 0.f;
        #pragma unroll
        for (int p8 = 0; p8 < 8; ++p8) s += Cs[p8*128 + tid];
        Zs[128 + tid] = s * inv;
      }
      __syncthreads();
      if (tid < V_){
        const float4* wr = (const float4*)(W_out + tid*256);
        float a = b_out[tid];
        #pragma unroll
        for (int k4 = 0; k4 < 64; ++k4){
          float4 q = wr[k4];
          a += q.x*Zs[k4*4+0] + q.y*Zs[k4*4+1] + q.z*Zs[k4*4+2] + q.w*Zs[k4*4+3];
        }
        Pr[tid] = a;
        out[((size_t)n*MAXLEN + step)*V_ + tid] = a;
      }
      __syncthreads();
      if (tid == 0){
        float bm = Pr[0]; int bi = 0;
        for (int v2 = 1; v2 < V_; ++v2){ float pv = Pr[v2]; if (pv > bm){ bm = pv; bi = v2; } }
        ((int*)red)[0] = bi;
      }
      __syncthreads();
      const int tok = ((int*)red)[0];
      cohstoref(Anxt + (size_t)n*ASTR + tid,       emb[(size_t)tok*H_ + tid]);
      cohstoref(Anxt + (size_t)n*ASTR + 256 + tid, emb[(size_t)tok*H_ + 256 + tid]);
    }
    gbar(slots, bflag, ++ep, b);

    // swap ping-pong A buffers
    float* tp = Acur; Acur = Anxt; Anxt = tp;
  }
}

extern "C" void kernel_launch(void* const* d_in, const int* in_sizes, int n_in,
                              void* d_out, int out_size, void* d_ws, size_t ws_size,
                              hipStream_t stream)
{
  const float* key    = (const float*)d_in[0];
  const float* val    = (const float*)d_in[1];
  const int*   lens   = (const int*)d_in[2];
  const float* emb    = (const float*)d_in[3];
  const float* W_ih1  = (const float*)d_in[4];
  const float* W_hh1  = (const float*)d_in[5];
  const float* b_ih1  = (const float*)d_in[6];
  const float* b_hh1  = (const float*)d_in[7];
  const float* W_ih2  = (const float*)d_in[8];
  const float* W_hh2  = (const float*)d_in[9];
  const float* b_ih2  = (const float*)d_in[10];
  const float* b_hh2  = (const float*)d_in[11];
  const float* W_out  = (const float*)d_in[12];
  const float* b_out  = (const float*)d_in[13];

  (void)in_sizes; (void)n_in; (void)out_size; (void)ws_size;

  (void)hipMemsetAsync(d_ws, 0, OFF_A0, stream);   // barrier slots + flag
  prep_state<<<128, 256, 0, stream>>>(val, emb, (char*)d_ws);
  decoder_main<<<NBLK, 256, 0, stream>>>(
      key, val, lens, emb, W_ih1, W_hh1, b_ih1, b_hh1,
      W_ih2, W_hh2, b_ih2, b_hh2, W_out, b_out,
      (float*)d_out, (char*)d_ws);
}

// Round 6
// 22256.079 us; speedup vs baseline: 1.9005x; 1.9005x over previous
//
#include <hip/hip_runtime.h>
#include <math.h>

typedef unsigned int u32;
typedef unsigned long long ull;
typedef float f4v __attribute__((ext_vector_type(4)));

#define T_     1024
#define N_     128
#define V_     35
#define H_     512
#define VS_    128
#define KS_    128
#define MAXLEN 250
#define NBLK   256
#define ASTR   1152   // A row: [emb(512) | vm(128) | h1(512)]

// ---- workspace layout (bytes) ----
#define OFF_FLAG  512
#define OFF_SLOTS 1024                  // 256 slots x 64B = 16384 -> 17408
#define OFF_HFLAG 17408                 // u32[128]
#define OFF_PFLAG 17920                 // u32[128]
#define OFF_PMS   18432                 // float[256] (m,s per n)
#define OFF_H2P   20480                 // float[128][128] = 64KB
#define OFF_PCTX  86016                 // float[128][128] = 64KB -> 151552
#define OFF_A0    151552
#define SZ_A      (N_*ASTR*4)           // 589824
#define OFF_A1    (OFF_A0+SZ_A)         // total ~1.27 MB

#define ASF_STR   1156                  // LDS A-tile stride (%32==4: kills bank conflicts)

__device__ __forceinline__ float sigf(float x){ return 1.0f/(1.0f+expf(-x)); }
__device__ __forceinline__ float dot4(float4 a, float4 b){ return a.x*b.x + a.y*b.y + a.z*b.z + a.w*b.w; }

// sc1 accessors: bypass stale L1/L2, hit coherent L3. ONLY for cross-block
// mutable state; read-only inputs keep plain cached loads (L2-resident).
__device__ __forceinline__ float cohloadf(const float* p){
  return __hip_atomic_load(p, __ATOMIC_RELAXED, __HIP_MEMORY_SCOPE_AGENT);
}
__device__ __forceinline__ void cohstoref(float* p, float v){
  __hip_atomic_store(p, v, __ATOMIC_RELAXED, __HIP_MEMORY_SCOPE_AGENT);
}
__device__ __forceinline__ ull cohloadu(const ull* p){
  return __hip_atomic_load(p, __ATOMIC_RELAXED, __HIP_MEMORY_SCOPE_AGENT);
}
__device__ __forceinline__ u32 cohloadw(const u32* p){
  return __hip_atomic_load(p, __ATOMIC_RELAXED, __HIP_MEMORY_SCOPE_AGENT);
}
__device__ __forceinline__ void cohstorew(u32* p, u32 v){
  __hip_atomic_store(p, v, __ATOMIC_RELAXED, __HIP_MEMORY_SCOPE_AGENT);
}

// Two-level flag barrier (no fences; __syncthreads' vmcnt(0) drain publishes).
__device__ __forceinline__ void gbar(u32* slots, u32* bflag, u32 ep, int b){
  __syncthreads();
  if (threadIdx.x == 0) cohstorew(&slots[(size_t)b*16], ep);
  if (b == 0){
    u32* ms = &slots[(size_t)threadIdx.x*16];
    while (cohloadw(ms) < ep) __builtin_amdgcn_s_sleep(1);
    __syncthreads();
    if (threadIdx.x == 0) cohstorew(bflag, ep);
  } else if (threadIdx.x == 0){
    while (cohloadw(bflag) < ep) __builtin_amdgcn_s_sleep(1);
  }
  __syncthreads();
}

// ---- one-time prep ----
__global__ void prep_state(const float* __restrict__ val, const float* __restrict__ emb,
                           char* __restrict__ ws){
  __shared__ float part[256];
  float* A0 = (float*)(ws + OFF_A0);
  float* A1 = (float*)(ws + OFF_A1);
  const int n = blockIdx.x, tid = threadIdx.x;
  const int c = tid >> 7, v = tid & 127;
  float acc = 0.f;
  const float* vp = val + (size_t)(c*512)*N_*VS_ + (size_t)n*VS_ + v;
  #pragma unroll 8
  for (int t = 0; t < 512; ++t) acc += vp[(size_t)t*N_*VS_];
  part[tid] = acc;
  __syncthreads();
  if (tid < 128){
    float vm = (part[tid] + part[tid+128]) * (1.0f/1024.0f);
    A0[(size_t)n*ASTR + 512 + tid] = vm;
    A1[(size_t)n*ASTR + 512 + tid] = vm;
  }
  A0[(size_t)n*ASTR + tid]       = emb[tid];        // emb[tok0=0]
  A0[(size_t)n*ASTR + 256 + tid] = emb[256 + tid];
  A0[(size_t)n*ASTR + 640 + tid] = 0.f;             // h1 = 0
  A0[(size_t)n*ASTR + 896 + tid] = 0.f;
}

// ---- persistent decoder: 256 blocks x 256 threads, 2 grid barriers/step ----
__global__ __launch_bounds__(256, 1) void decoder_main(
  const float* __restrict__ key, const float* __restrict__ val,
  const int* __restrict__ lens, const float* __restrict__ emb,
  const float* __restrict__ W_ih1, const float* __restrict__ W_hh1,
  const float* __restrict__ b_ih1, const float* __restrict__ b_hh1,
  const float* __restrict__ W_ih2, const float* __restrict__ W_hh2,
  const float* __restrict__ b_ih2, const float* __restrict__ b_hh2,
  const float* __restrict__ W_out, const float* __restrict__ b_out,
  float* __restrict__ out, char* __restrict__ ws)
{
  // Phase A: AsF[16][1156] + Ws[64][68]. Phase BC overlays the front.
  __shared__ __align__(16) float smem[16*ASF_STR + 64*68];   // 22848 floats = 91.4KB
  __shared__ float c1_keep[256];
  __shared__ float h2_keep[128];
  __shared__ float c2_keep[128];
  float* AsF = smem;
  float* Ws  = smem + 16*ASF_STR;

  u32* bflag  = (u32*)(ws + OFF_FLAG);
  u32* slots  = (u32*)(ws + OFF_SLOTS);
  u32* hflag  = (u32*)(ws + OFF_HFLAG);
  u32* pflag  = (u32*)(ws + OFF_PFLAG);
  float* pms  = (float*)(ws + OFF_PMS);
  float* h2p  = (float*)(ws + OFF_H2P);
  float* pctx = (float*)(ws + OFF_PCTX);
  float* A0   = (float*)(ws + OFF_A0);
  float* A1   = (float*)(ws + OFF_A1);

  const int b = blockIdx.x;
  const int tid = threadIdx.x;

  c1_keep[tid] = 0.f;
  if (tid < 128){ h2_keep[tid] = 0.f; c2_keep[tid] = 0.f; }

  float* Acur = A0; float* Anxt = A1;
  u32 ep = 0;

  #pragma unroll 1
  for (int step = 0; step < MAXLEN; ++step){
    // ============ Phase A: LSTM1 gates, all 256 blocks ============
    {
      const int rt = b >> 5, ct = b & 31;
      const int row0 = rt*16, c0 = ct*64;
      const int lane = tid & 63, qw = tid >> 6;
      const int r_g = lane >> 4;
      const int c_g = lane & 15;
      const int c_st = tid >> 2, seg = tid & 3;
      const int sgl = c0 + c_st, shh = sgl >> 2, sgg = sgl & 3;
      const float* wsx = W_ih1 + (size_t)(sgg*H_ + shh)*640 + seg*16;
      const float* wsh = W_hh1 + (size_t)(sgg*H_ + shh)*512 + seg*16;

      float4 w0,w1,w2,w3;
      w0 = ((const float4*)wsx)[0]; w1 = ((const float4*)wsx)[1];
      w2 = ((const float4*)wsx)[2]; w3 = ((const float4*)wsx)[3];

      { // stage full A-tile (16 x 1152) into LDS via batched sc1 loads
        const int r = tid >> 4, sub = tid & 15;
        const ull* src = (const ull*)(Acur + (size_t)(row0 + r)*ASTR + sub*72);
        ull* dst = (ull*)(AsF + r*ASF_STR + sub*72);
        #pragma unroll
        for (int jj = 0; jj < 36; jj += 9){
          ull t0=cohloadu(src+jj+0), t1=cohloadu(src+jj+1), t2=cohloadu(src+jj+2),
              t3=cohloadu(src+jj+3), t4u=cohloadu(src+jj+4), t5=cohloadu(src+jj+5),
              t6=cohloadu(src+jj+6), t7=cohloadu(src+jj+7), t8=cohloadu(src+jj+8);
          dst[jj+0]=t0; dst[jj+1]=t1; dst[jj+2]=t2; dst[jj+3]=t3; dst[jj+4]=t4u;
          dst[jj+5]=t5; dst[jj+6]=t6; dst[jj+7]=t7; dst[jj+8]=t8;
        }
      }

      float acc[4][4];
      #pragma unroll
      for (int i = 0; i < 4; ++i){ acc[i][0]=0.f; acc[i][1]=0.f; acc[i][2]=0.f; acc[i][3]=0.f; }

      #pragma unroll 1
      for (int ch = 0; ch < 18; ++ch){
        __syncthreads();
        { float* wd = Ws + c_st*68 + seg*16;
          ((float4*)wd)[0]=w0; ((float4*)wd)[1]=w1; ((float4*)wd)[2]=w2; ((float4*)wd)[3]=w3;
        }
        __syncthreads();
        if (ch < 17){
          int kb = (ch+1)*64;
          const float* p = (kb < 640) ? (wsx + kb) : (wsh + (kb-640));
          w0 = ((const float4*)p)[0]; w1 = ((const float4*)p)[1];
          w2 = ((const float4*)p)[2]; w3 = ((const float4*)p)[3];
        }
        const int kbase = ch*64;
        #pragma unroll
        for (int kq = 0; kq < 4; ++kq){
          const int t4 = (qw*4 + kq)*4;
          float4 wv0 = *(const float4*)(Ws + (c_g   )*68 + t4);
          float4 wv1 = *(const float4*)(Ws + (c_g+16)*68 + t4);
          float4 wv2 = *(const float4*)(Ws + (c_g+32)*68 + t4);
          float4 wv3 = *(const float4*)(Ws + (c_g+48)*68 + t4);
          const int ko = kbase + t4;
          float4 av0 = *(const float4*)(AsF + (r_g   )*ASF_STR + ko);
          float4 av1 = *(const float4*)(AsF + (r_g+ 4)*ASF_STR + ko);
          float4 av2 = *(const float4*)(AsF + (r_g+ 8)*ASF_STR + ko);
          float4 av3 = *(const float4*)(AsF + (r_g+12)*ASF_STR + ko);
          acc[0][0]+=dot4(av0,wv0); acc[0][1]+=dot4(av0,wv1); acc[0][2]+=dot4(av0,wv2); acc[0][3]+=dot4(av0,wv3);
          acc[1][0]+=dot4(av1,wv0); acc[1][1]+=dot4(av1,wv1); acc[1][2]+=dot4(av1,wv2); acc[1][3]+=dot4(av1,wv3);
          acc[2][0]+=dot4(av2,wv0); acc[2][1]+=dot4(av2,wv1); acc[2][2]+=dot4(av2,wv2); acc[2][3]+=dot4(av2,wv3);
          acc[3][0]+=dot4(av3,wv0); acc[3][1]+=dot4(av3,wv1); acc[3][2]+=dot4(av3,wv2); acc[3][3]+=dot4(av3,wv3);
        }
      }
      __syncthreads();
      float* Red = Ws;   // [a(16)][q(4)][lane(64)] = 4096 floats
      #pragma unroll
      for (int ri = 0; ri < 4; ++ri)
        #pragma unroll
        for (int ci = 0; ci < 4; ++ci)
          Red[((ri*4+ci)*4 + qw)*64 + lane] = acc[ri][ci];
      __syncthreads();
      float* Gs = AsF;   // reuse, stride 68
      { const int l2 = tid & 63, g = tid >> 6;
        const int row_l = (l2 >> 4) + 4*g;
        #pragma unroll
        for (int j = 0; j < 4; ++j){
          const int a = g*4 + j;
          const float* rp = Red + a*256 + l2;
          float s = rp[0] + rp[64] + rp[128] + rp[192];
          const int col_l = (l2 & 15) + 16*j;
          const int cgl = c0 + col_l, chh2 = cgl >> 2, cgg2 = cgl & 3;
          s += b_ih1[cgg2*H_ + chh2] + b_hh1[cgg2*H_ + chh2];
          Gs[row_l*68 + col_l] = s;
        }
      }
      __syncthreads();
      { const int r = tid >> 4, hl = tid & 15;
        float4 q = *(const float4*)(Gs + r*68 + hl*4);   // i,f,g,o
        const int row = row0 + r, hid = ct*16 + hl;
        float cold = c1_keep[tid];
        float cn = sigf(q.y)*cold + sigf(q.x)*tanhf(q.z);
        float hn = sigf(q.w)*tanhf(cn);
        c1_keep[tid] = cn;
        cohstoref(Anxt + (size_t)row*ASTR + 640 + hid, hn);
      }
    }
    gbar(slots, bflag, ++ep, b);

    // ===== Phase BC: pair (n, n+128) splits attention; owner = b<128 =====
    {
      const int n = b & 127;
      const bool owner = (b < 128);
      float* xs   = smem;          // [640] owner: [h1 | h2old]
      float* ctxL = smem + 640;    // [128] local unnorm ctx (owner G2 reuses)
      float* G2   = smem + 640;    // [512] owner gate pre-acts (done before ctxL)
      float* h2s  = smem + 1152;   // [128]
      float* Es   = smem + 1280;   // [1024]
      float* red  = smem + 2304;   // [256]
      float* Cs   = smem + 2560;   // [8][128]
      float* Zs   = smem + 3584;   // [256] = [h2 | ctx]
      float* Pr   = smem + 3840;   // [64] logits
      const int len = lens[n];
      const int mid = (len + 1) >> 1;
      const int lo = owner ? 0 : mid;
      const int hi = owner ? mid : len;

      if (owner){
        xs[tid]       = cohloadf(Anxt + (size_t)n*ASTR + 640 + tid);
        xs[256 + tid] = cohloadf(Anxt + (size_t)n*ASTR + 896 + tid);
        if (tid < 128) xs[512 + tid] = h2_keep[tid];
        __syncthreads();
        { float fa = b_ih2[tid]     + b_hh2[tid];
          float fb = b_ih2[256+tid] + b_hh2[256+tid];
          const float4* wa = (const float4*)(W_ih2 + (size_t)tid*512);
          const float4* wb = (const float4*)(W_ih2 + (size_t)(256+tid)*512);
          const float4* xv4 = (const float4*)xs;
          #pragma unroll 8
          for (int k4 = 0; k4 < 128; ++k4){
            float4 xv = xv4[k4];
            fa += dot4(wa[k4], xv);
            fb += dot4(wb[k4], xv);
          }
          const float4* ha = (const float4*)(W_hh2 + (size_t)tid*128);
          const float4* hb = (const float4*)(W_hh2 + (size_t)(256+tid)*128);
          #pragma unroll 8
          for (int k4 = 0; k4 < 32; ++k4){
            float4 xv = xv4[128 + k4];
            fa += dot4(ha[k4], xv);
            fb += dot4(hb[k4], xv);
          }
          G2[tid] = fa; G2[256+tid] = fb;
        }
        __syncthreads();
        if (tid < 128){
          float gi = G2[tid], gf = G2[128+tid], gg = G2[256+tid], go = G2[384+tid];
          float cold = c2_keep[tid];
          float cn = sigf(gf)*cold + sigf(gi)*tanhf(gg);
          float hn = sigf(go)*tanhf(cn);
          c2_keep[tid] = cn; h2_keep[tid] = hn;
          h2s[tid] = hn;
          cohstoref(h2p + (size_t)n*128 + tid, hn);   // publish h2 to helper
        }
        __syncthreads();                              // drains sc1 stores
        if (tid == 0) cohstorew(&hflag[n], (u32)(step+1));
      } else {
        if (tid == 0){
          while (cohloadw(&hflag[n]) < (u32)(step+1)) __builtin_amdgcn_s_sleep(1);
        }
        __syncthreads();
        if (tid < 128) h2s[tid] = cohloadf(h2p + (size_t)n*128 + tid);
        __syncthreads();
      }

      // --- energies over [lo, hi) ---
      for (int t = lo + tid; t < hi; t += 256){
        const float4* kp = (const float4*)(key + ((size_t)t*N_ + n)*KS_);
        float e = 0.f;
        #pragma unroll
        for (int k4 = 0; k4 < 32; ++k4){
          float4 q = kp[k4];
          e += q.x*h2s[k4*4+0] + q.y*h2s[k4*4+1] + q.z*h2s[k4*4+2] + q.w*h2s[k4*4+3];
        }
        Es[t] = e;
      }
      __syncthreads();
      // --- local max / sum over [lo, hi) ---
      float lm = -3.0e38f;
      for (int t = lo + tid; t < hi; t += 256) lm = fmaxf(lm, Es[t]);
      red[tid] = lm; __syncthreads();
      for (int s2 = 128; s2 > 0; s2 >>= 1){ if (tid < s2) red[tid] = fmaxf(red[tid], red[tid+s2]); __syncthreads(); }
      const float m_l = red[0];
      __syncthreads();
      float ls = 0.f;
      for (int t = lo + tid; t < hi; t += 256){ float p = expf(Es[t]-m_l); Es[t] = p; ls += p; }
      red[tid] = ls; __syncthreads();
      for (int s2 = 128; s2 > 0; s2 >>= 1){ if (tid < s2) red[tid] += red[tid+s2]; __syncthreads(); }
      const float s_l = red[0];
      __syncthreads();
      // --- unnormalized ctx partial: 4x unrolled, 4 loads in flight ---
      { const int part = tid >> 5, v4 = (tid & 31)*4;
        f4v a0 = {0.f,0.f,0.f,0.f}, a1 = a0, a2 = a0, a3 = a0;
        int t = lo + part;
        for (; t + 24 < hi; t += 32){
          float p0 = Es[t], p1 = Es[t+8], p2 = Es[t+16], p3 = Es[t+24];
          f4v u0 = *(const f4v*)(val + ((size_t)(t    )*N_ + n)*VS_ + v4);
          f4v u1 = *(const f4v*)(val + ((size_t)(t+ 8 )*N_ + n)*VS_ + v4);
          f4v u2 = *(const f4v*)(val + ((size_t)(t+16 )*N_ + n)*VS_ + v4);
          f4v u3 = *(const f4v*)(val + ((size_t)(t+24 )*N_ + n)*VS_ + v4);
          a0 += p0*u0; a1 += p1*u1; a2 += p2*u2; a3 += p3*u3;
        }
        for (; t < hi; t += 8){
          f4v u0 = *(const f4v*)(val + ((size_t)t*N_ + n)*VS_ + v4);
          a0 += Es[t]*u0;
        }
        f4v ct = a0 + a1 + a2 + a3;
        Cs[part*128 + v4+0]=ct.x; Cs[part*128 + v4+1]=ct.y;
        Cs[part*128 + v4+2]=ct.z; Cs[part*128 + v4+3]=ct.w;
      }
      __syncthreads();
      if (tid < 128){
        float s = 0.f;
        #pragma unroll
        for (int p8 = 0; p8 < 8; ++p8) s += Cs[p8*128 + tid];
        ctxL[tid] = s;
      }
      __syncthreads();

      if (!owner){
        // publish partial (m, s, ctx)
        if (tid < 128) cohstoref(pctx + (size_t)n*128 + tid, ctxL[tid]);
        if (tid == 0){ cohstoref(pms + 2*n, m_l); cohstoref(pms + 2*n + 1, s_l); }
        __syncthreads();                            // drains sc1 stores
        if (tid == 0) cohstorew(&pflag[n], (u32)(step+1));
      } else {
        if (tid == 0){
          while (cohloadw(&pflag[n]) < (u32)(step+1)) __builtin_amdgcn_s_sleep(1);
        }
        __syncthreads();
        if (tid < 128){
          float m2 = cohloadf(pms + 2*n), s2v = cohloadf(pms + 2*n + 1);
          float c2v = cohloadf(pctx + (size_t)n*128 + tid);
          float m = fmaxf(m_l, m2);
          float e1 = expf(m_l - m), e2 = expf(m2 - m);
          float denom = e1*s_l + e2*s2v;
          Zs[tid]       = h2s[tid];
          Zs[128 + tid] = (e1*ctxL[tid] + e2*c2v) / denom;
        }
        __syncthreads();
        if (tid < V_){
          const float4* wr = (const float4*)(W_out + tid*256);
          float a = b_out[tid];
          #pragma unroll
          for (int k4 = 0; k4 < 64; ++k4){
            float4 q = wr[k4];
            a += q.x*Zs[k4*4+0] + q.y*Zs[k4*4+1] + q.z*Zs[k4*4+2] + q.w*Zs[k4*4+3];
          }
          Pr[tid] = a;
          out[((size_t)n*MAXLEN + step)*V_ + tid] = a;
        }
        __syncthreads();
        if (tid == 0){
          float bm = Pr[0]; int bi = 0;
          for (int v2 = 1; v2 < V_; ++v2){ float pv = Pr[v2]; if (pv > bm){ bm = pv; bi = v2; } }
          ((int*)red)[0] = bi;
        }
        __syncthreads();
        const int tok = ((int*)red)[0];
        cohstoref(Anxt + (size_t)n*ASTR + tid,       emb[(size_t)tok*H_ + tid]);
        cohstoref(Anxt + (size_t)n*ASTR + 256 + tid, emb[(size_t)tok*H_ + 256 + tid]);
      }
    }
    gbar(slots, bflag, ++ep, b);

    // swap ping-pong A buffers
    float* tp = Acur; Acur = Anxt; Anxt = tp;
  }
}

extern "C" void kernel_launch(void* const* d_in, const int* in_sizes, int n_in,
                              void* d_out, int out_size, void* d_ws, size_t ws_size,
                              hipStream_t stream)
{
  const float* key    = (const float*)d_in[0];
  const float* val    = (const float*)d_in[1];
  const int*   lens   = (const int*)d_in[2];
  const float* emb    = (const float*)d_in[3];
  const float* W_ih1  = (const float*)d_in[4];
  const float* W_hh1  = (const float*)d_in[5];
  const float* b_ih1  = (const float*)d_in[6];
  const float* b_hh1  = (const float*)d_in[7];
  const float* W_ih2  = (const float*)d_in[8];
  const float* W_hh2  = (const float*)d_in[9];
  const float* b_ih2  = (const float*)d_in[10];
  const float* b_hh2  = (const float*)d_in[11];
  const float* W_out  = (const float*)d_in[12];
  const float* b_out  = (const float*)d_in[13];

  (void)in_sizes; (void)n_in; (void)out_size; (void)ws_size;

  (void)hipMemsetAsync(d_ws, 0, OFF_H2P, stream);   // barrier slots + pair flags
  prep_state<<<128, 256, 0, stream>>>(val, emb, (char*)d_ws);
  decoder_main<<<NBLK, 256, 0, stream>>>(
      key, val, lens, emb, W_ih1, W_hh1, b_ih1, b_hh1,
      W_ih2, W_hh2, b_ih2, b_hh2, W_out, b_out,
      (float*)d_out, (char*)d_ws);
}